// Round 21
// baseline (206.736 us; speedup 1.0000x reference)
//
#include <hip/hip_runtime.h>
#include <cstdio>
#include <cstdint>

typedef unsigned long long u64;
typedef unsigned short u16;
typedef unsigned int u32;

// ---------------- problem constants ----------------
static const int kNV = 200000;
static const int kNT = 800000;
static const int kNUV = 895;                       // ceil(sqrt((2*NT+1)//2))
#define UVS_ROWS   3204100LL                       // kNUV*kNUV*4
#define UVS_FLOATS 6408200LL                       // UVS_ROWS*2
#define CAP 3300000                                // max crossing-edge instances (<= 4*NT = 3.2M)

// counting-sort geometry (R15-proven)
#define NH 392                                     // classify blocks
#define TILE_T 2048                                // tets per classify block
#define NH2 98                                     // scatter blocks (4 classify blocks each)
#define TILE_T2 8192                               // tets per scatter block
#define SBLK 1024                                  // scatter block threads (16 waves)
#define BINW 64                                    // a-values per coarse bin
#define BSH 6                                      // log2(BINW)
#define NBIN 3125                                  // 200000/64
#define SUBSH 15                                   // group key = (a, b>>SUBSH) == fine key
#define FINEB 512                                  // BINW * (1<<(18-SUBSH)) fine cursors
#define MAXBIN 2816                                // LDS bin capacity
#define C 11                                       // MAXBIN/256 items per thread

__device__ const int c_tri[16][6] = {
    {-1,-1,-1,-1,-1,-1},{1,0,2,-1,-1,-1},{4,0,3,-1,-1,-1},{1,4,2,1,3,4},
    {3,1,5,-1,-1,-1},{2,3,0,2,5,3},{1,4,0,1,5,4},{4,2,5,-1,-1,-1},
    {4,5,2,-1,-1,-1},{4,1,0,4,5,1},{3,2,0,3,5,2},{1,3,5,-1,-1,-1},
    {4,1,2,4,3,1},{3,0,4,-1,-1,-1},{2,0,1,-1,-1,-1},{-1,-1,-1,-1,-1,-1}};
__device__ const int c_ntri[16]   = {0,1,1,2,1,2,2,1,1,2,2,1,2,1,1,0};
__device__ const int c_ncross[16] = {0,3,3,4,3,4,4,3,3,4,4,3,4,3,3,0};
__device__ const int c_edges[12] = {0,1,0,2,0,3,1,2,1,3,2,3};

// psum packing: m1 <<44 | m2 <<24 | ncross
#define PK(m1,m2,nc) (((u64)(m1) << 44) | ((u64)(m2) << 24) | (u64)(nc))
// ebin packing: a <<40 | b <<22 | seq
// meta16BySeq: rp only; bin recomputed in k_faces from tet

// block-wide exclusive scan of one int per thread (256 thr) via shfl; 2 barriers.
__device__ __forceinline__ int blockScanExcl(int v, volatile int* wsum, int tid, int* totalOut){
  int lane = tid & 63, wv = tid >> 6;
  int x = v;
  #pragma unroll
  for (int off = 1; off < 64; off <<= 1){
    int t = __shfl_up(x, off, 64);
    if (lane >= off) x += t;
  }
  __syncthreads();                 // protect wsum from prior use
  if (lane == 63) wsum[wv] = x;
  __syncthreads();
  int carry = 0;
  #pragma unroll
  for (int w = 0; w < 4; w++) if (w < wv) carry += wsum[w];
  if (totalOut) *totalOut = wsum[0] + wsum[1] + wsum[2] + wsum[3];
  return carry + x - v;
}

// ---------------- generic exclusive scan (templated, 3 kernels) ----------------
#define SCAN_B 256
#define SCAN_I 8
#define SCAN_TILE (SCAN_B*SCAN_I)

template<typename T>
__global__ void k_scan_partial(const T* __restrict__ in, T* __restrict__ partials, int n){
  __shared__ T sm[SCAN_B];
  int b = blockIdx.x;
  long long base = (long long)b*SCAN_TILE;
  T sum = 0;
  for (int i = threadIdx.x; i < SCAN_TILE; i += SCAN_B){
    long long idx = base + i;
    if (idx < n) sum += in[idx];
  }
  sm[threadIdx.x] = sum; __syncthreads();
  for (int s = SCAN_B/2; s > 0; s >>= 1){
    if ((int)threadIdx.x < s) sm[threadIdx.x] += sm[threadIdx.x + s];
    __syncthreads();
  }
  if (threadIdx.x == 0) partials[b] = sm[0];
}

template<typename T>
__global__ void k_scan_blocksums(T* __restrict__ partials, int nb, T* __restrict__ total_out){
  __shared__ T sm[SCAN_B];
  T carry = 0;
  for (int base = 0; base < nb; base += SCAN_B){
    int i = base + (int)threadIdx.x;
    T v = (i < nb) ? partials[i] : (T)0;
    sm[threadIdx.x] = v; __syncthreads();
    for (int off = 1; off < SCAN_B; off <<= 1){
      T t = ((int)threadIdx.x >= off) ? sm[threadIdx.x - off] : (T)0;
      __syncthreads();
      sm[threadIdx.x] += t;
      __syncthreads();
    }
    if (i < nb) partials[i] = carry + sm[threadIdx.x] - v;  // exclusive
    T tilesum = sm[SCAN_B-1];
    __syncthreads();
    carry += tilesum;
  }
  if (threadIdx.x == 0 && total_out) *total_out = carry;
}

template<typename T>
__global__ void k_scan_apply(const T* __restrict__ in, T* __restrict__ out,
                             const T* __restrict__ partials, int n){
  __shared__ T sm[SCAN_B];
  int b = blockIdx.x;
  long long base = (long long)b*SCAN_TILE + (long long)threadIdx.x*SCAN_I;
  T v[SCAN_I]; T s = 0;
  #pragma unroll
  for (int k = 0; k < SCAN_I; k++){ long long idx = base + k; v[k] = (idx < n) ? in[idx] : (T)0; s += v[k]; }
  sm[threadIdx.x] = s; __syncthreads();
  for (int off = 1; off < 256; off <<= 1){
    T t = ((int)threadIdx.x >= off) ? sm[threadIdx.x - off] : (T)0;
    __syncthreads();
    sm[threadIdx.x] += t;
    __syncthreads();
  }
  T excl = sm[threadIdx.x] - s + partials[b];
  #pragma unroll
  for (int k = 0; k < SCAN_I; k++){ long long idx = base + k; if (idx < n) out[idx] = excl; excl += v[k]; }
}

template<typename T>
static void run_scan(const T* in, T* out, int n, T* partials, hipStream_t s){
  int nb = (n + SCAN_TILE - 1) / SCAN_TILE;
  k_scan_partial<T><<<nb, SCAN_B, 0, s>>>(in, partials, n);
  k_scan_blocksums<T><<<1, SCAN_B, 0, s>>>(partials, nb, out + n);  // total -> out[n]
  k_scan_apply<T><<<nb, SCAN_B, 0, s>>>(in, out, partials, n);
}

// psum apply: recompute PK values from tetinfo (no pk array); partials = pre-scanned pkPart
__global__ void k_scan_apply_pk(const int* __restrict__ tetinfo, u64* __restrict__ out,
                                const u64* __restrict__ partials){
  __shared__ u64 sm[SCAN_B];
  int b = blockIdx.x;
  long long base = (long long)b*SCAN_TILE + (long long)threadIdx.x*SCAN_I;
  u64 v[SCAN_I]; u64 s = 0;
  #pragma unroll
  for (int k = 0; k < SCAN_I; k++){
    long long idx = base + k;
    if (idx < kNT){
      int pat = tetinfo[idx];
      int nt_ = c_ntri[pat];
      v[k] = PK(nt_ == 1, nt_ == 2, c_ncross[pat]);
    } else v[k] = 0;
    s += v[k];
  }
  sm[threadIdx.x] = s; __syncthreads();
  for (int off = 1; off < 256; off <<= 1){
    u64 t = ((int)threadIdx.x >= off) ? sm[threadIdx.x - off] : (u64)0;
    __syncthreads();
    sm[threadIdx.x] += t;
    __syncthreads();
  }
  u64 excl = sm[threadIdx.x] - s + partials[b];
  #pragma unroll
  for (int k = 0; k < SCAN_I; k++){ long long idx = base + k; if (idx < kNT) out[idx] = excl; excl += v[k]; }
}

// ---------------- pipeline kernels ----------------

// fused: per-tet pattern + coarse-bin histogram (bin-major for the generic scan) + PK sums
__global__ void k_classify_hist(const int* __restrict__ tet, const float* __restrict__ sdf,
                                int* __restrict__ tetinfo, int* __restrict__ blockHist,
                                u64* __restrict__ pkPart){
  __shared__ int h[NBIN];
  __shared__ u64 red[256];
  int blk = blockIdx.x;
  for (int j = threadIdx.x; j < NBIN; j += 256) h[j] = 0;
  __syncthreads();
  int t0 = blk*TILE_T;
  u64 myPk = 0;
  for (int k = 0; k < TILE_T/256; k++){
    int t = t0 + k*256 + threadIdx.x;
    if (t < kNT){
      int4 v4 = ((const int4*)tet)[t];
      int pat = ((sdf[v4.x] > 0.0f) ? 1 : 0) | ((sdf[v4.y] > 0.0f) ? 2 : 0)
              | ((sdf[v4.z] > 0.0f) ? 4 : 0) | ((sdf[v4.w] > 0.0f) ? 8 : 0);
      tetinfo[t] = pat;
      int nt_ = c_ntri[pat];
      myPk += PK(nt_ == 1, nt_ == 2, c_ncross[pat]);
      if (pat != 0 && pat != 15){
        int vv[4] = {v4.x, v4.y, v4.z, v4.w};
        #pragma unroll
        for (int e = 0; e < 6; e++){
          int i0 = c_edges[2*e], i1 = c_edges[2*e+1];
          if (((pat >> i0) & 1) != ((pat >> i1) & 1)){
            int a = vv[i0], b = vv[i1]; if (a > b){ int tm = a; a = b; b = tm; }
            atomicAdd(&h[a >> BSH], 1);
          }
        }
      }
    }
  }
  red[threadIdx.x] = myPk;
  __syncthreads();
  for (int s = 128; s > 0; s >>= 1){
    if ((int)threadIdx.x < s) red[threadIdx.x] += red[threadIdx.x + s];
    __syncthreads();
  }
  if (threadIdx.x == 0) pkPart[blk] = red[0];
  for (int j = threadIdx.x; j < NBIN; j += 256) blockHist[j*NH + blk] = h[j];  // bin-major
}

// scatter: 98 fat blocks (4 classify-blocks each) -> per-(block,bin) runs of ~8 items
// => full 64B lines, ~1x write amplification. Cursor = bhScan at first merged block.
__global__ void k_scatter(const int* __restrict__ tet, const int* __restrict__ tetinfo,
                          const u64* __restrict__ psum, const int* __restrict__ bhScan,
                          u64* __restrict__ ebin){
  __shared__ int c[NBIN];
  int blk = blockIdx.x;
  for (int j = threadIdx.x; j < NBIN; j += SBLK)
    c[j] = bhScan[j*NH + 4*blk];        // prefix at first of the 4 merged classify blocks
  __syncthreads();
  int t0 = blk*TILE_T2;
  for (int k = 0; k < TILE_T2/SBLK; k++){
    int t = t0 + k*SBLK + threadIdx.x;
    if (t < kNT){
      int pat = tetinfo[t];
      if (pat != 0 && pat != 15){
        int4 v4 = ((const int4*)tet)[t];
        int vv[4] = {v4.x, v4.y, v4.z, v4.w};
        int seq = (int)(psum[t] & 0xFFFFFF);
        #pragma unroll
        for (int e = 0; e < 6; e++){
          int i0 = c_edges[2*e], i1 = c_edges[2*e+1];
          if (((pat >> i0) & 1) != ((pat >> i1) & 1)){
            int a = vv[i0], b = vv[i1]; if (a > b){ int tm = a; a = b; b = tm; }
            int pos = atomicAdd(&c[a >> BSH], 1);
            ebin[pos] = ((u64)(unsigned)a << 40) | ((u64)(unsigned)b << 22) | (unsigned)seq;
            seq++;
          }
        }
      }
    }
  }
}

// per coarse bin: register-staged fine regroup + two-phase first/rank via h-run boundaries,
// DIRECT outputs: meta16 scatter (rp by seq) + compacted per-bin firsts stream vfirst.
__global__ void k_fineflags(const int* __restrict__ bhScan, const u64* __restrict__ ebin,
                            u16* __restrict__ meta16, u64* __restrict__ vfirst,
                            int* __restrict__ binFirstCnt){
  __shared__ u64 ld[MAXBIN];             // 22.5 KB
  __shared__ unsigned char fl[MAXBIN];   // 2.8 KB  first flags
  __shared__ u16 fp[MAXBIN];             // 5.6 KB  exclusive prefix of fl
  __shared__ int h[FINEB];               // 2 KB    fine-key cursors / run ends
  __shared__ int wsum[4];
  int bin = blockIdx.x, tid = threadIdx.x;
  int bs = bhScan[bin*NH];
  int be = bhScan[(bin+1)*NH];           // scan stores total at [n] for the last bin
  int n = be - bs;
  int a0 = bin << BSH;
  for (int j = tid; j < FINEB; j += 256) h[j] = 0;
  __syncthreads();
  if (n <= MAXBIN){
    // stage bin into registers (single ebin pass) + fine keys
    u64 pr[C]; int kr[C];
    #pragma unroll
    for (int k = 0; k < C; k++){
      int i = tid + k*256;
      if (i < n){
        u64 p = ebin[bs + i];
        pr[k] = p;
        kr[k] = (((int)(p >> 40) - a0) << 3) | ((int)((p >> 22) & 0x3FFFF) >> SUBSH);
      } else kr[k] = -1;
    }
    // hist
    #pragma unroll
    for (int k = 0; k < C; k++) if (kr[k] >= 0) atomicAdd(&h[kr[k]], 1);
    __syncthreads();
    // exclusive scan of h[512] (2/thread, shfl-based)
    int s0 = h[2*tid], s1 = h[2*tid+1];
    int excl = blockScanExcl(s0 + s1, wsum, tid, nullptr);
    h[2*tid] = excl; h[2*tid+1] = excl + s0;
    __syncthreads();
    // scatter from registers into LDS
    #pragma unroll
    for (int k = 0; k < C; k++)
      if (kr[k] >= 0) ld[atomicAdd(&h[kr[k]], 1)] = pr[k];
    __syncthreads();
    // phase A: first flags via backward dup-scan [gs, x)
    #pragma unroll
    for (int k = 0; k < C; k++){
      int x = tid + k*256;
      if (x < n){
        u64 my = ld[x] >> 22;
        int key = (((int)(my >> 18) - a0) << 3) | ((int)(my & 0x3FFFF) >> SUBSH);
        int gs = key ? h[key-1] : 0;
        unsigned char f = 1;
        for (int y = x-1; y >= gs; y--){ if ((ld[y] >> 22) == my){ f = 0; break; } }
        fl[x] = f;
      } else if (x < MAXBIN) fl[x] = 0;
    }
    __syncthreads();
    // phase B: chunked exclusive prefix of fl (shfl-based)
    int cbase = tid*C;
    int loc[C]; int cs = 0;
    #pragma unroll
    for (int q = 0; q < C; q++){ loc[q] = fl[cbase+q]; cs += loc[q]; }
    int tot;
    int ex2 = blockScanExcl(cs, wsum, tid, &tot);
    #pragma unroll
    for (int q = 0; q < C; q++){ fp[cbase+q] = (u16)ex2; ex2 += loc[q]; }
    if (tid == 0) binFirstCnt[bin] = tot;
    __syncthreads();
    // phase C: rank over [gs, ge) using fl; scatter meta16 + compacted firsts (by rp)
    #pragma unroll
    for (int k = 0; k < C; k++){
      int x = tid + k*256;
      if (x < n){
        u64 p = ld[x];
        u64 my = p >> 22;
        int key = (((int)(my >> 18) - a0) << 3) | ((int)(my & 0x3FFFF) >> SUBSH);
        int gs = key ? h[key-1] : 0;
        int ge = h[key];
        int rk = 0;
        for (int y = gs; y < ge; y++){ if (fl[y] && (ld[y] >> 22) < my) rk++; }
        int rp = (int)fp[gs] + rk;        // bin-local sorted rank of this distinct edge
        meta16[(int)(p & 0x3FFFFF)] = (u16)rp;
        if (fl[x]) vfirst[bs + rp] = p;   // rp bijective over firsts -> sorted stream
      }
    }
  } else {
    // fallback (statistically never): serial O(n^2) by thread 0 straight from ebin
    if (tid == 0){
      int fcnt = 0;
      for (int x = 0; x < n; x++){
        u64 px = ebin[bs+x];
        u64 kx = px >> 22;
        int f = 1;
        for (int y = 0; y < x; y++) if ((ebin[bs+y] >> 22) == kx){ f = 0; break; }
        int rp = 0;
        for (int y = 0; y < n; y++){
          u64 ky = ebin[bs+y] >> 22;
          if (ky < kx){
            int fy = 1;
            for (int z = 0; z < y; z++) if ((ebin[bs+z] >> 22) == ky){ fy = 0; break; }
            rp += fy;
          }
        }
        if (f){ vfirst[bs + rp] = px; fcnt++; }
        meta16[(int)(px & 0x3FFFFF)] = (u16)rp;
      }
      binFirstCnt[bin] = fcnt;
    }
  }
}

// per-bin verts: sequential reads of compacted firsts; sequential vert writes
__global__ void k_verts(const int* __restrict__ bhScan, const u64* __restrict__ vfirst,
                        const int* __restrict__ binPref, const float* __restrict__ pos,
                        const float* __restrict__ sdf, float* __restrict__ out){
  int bin = blockIdx.x;
  int bs = bhScan[bin*NH];
  int rbase = binPref[bin];
  int cnt = binPref[bin+1] - rbase;
  for (int f = threadIdx.x; f < cnt; f += 256){
    u64 p = vfirst[bs + f];
    int a = (int)(p >> 40);
    int b = (int)((p >> 22) & 0x3FFFF);
    float sa = sdf[a], sb = sdf[b];
    float denom = sa - sb;               // s = [sa,-sb]; never 0 for a crossing edge
    float w0 = (-sb) / denom;
    float w1 = sa / denom;
    long long r = rbase + f;
    out[3*r + 0] = pos[3*a+0]*w0 + pos[3*b+0]*w1;
    out[3*r + 1] = pos[3*a+1]*w0 + pos[3*b+1]*w1;
    out[3*r + 2] = pos[3*a+2]*w0 + pos[3*b+2]*w1;
  }
}

// faces + uv_idx: recompute bin from tet (a>>BSH); r = binPref[bin] + meta16[seq+j]
__global__ void k_faces(const int* __restrict__ tet, const int* __restrict__ tetinfo,
                        const u64* __restrict__ psum, const int* __restrict__ binPref,
                        const u16* __restrict__ meta16, float* __restrict__ out){
  int t = blockIdx.x*256 + threadIdx.x; if (t >= kNT) return;
  int pat = tetinfo[t];
  int nt_ = c_ntri[pat];
  if (nt_ == 0) return;
  u64 tot = psum[kNT];
  int Nm1 = (int)(tot >> 44), Nm2 = (int)((tot >> 24) & 0xFFFFF);
  int Ne = binPref[NBIN];
  long long faces_off = 3LL*Ne;
  long long uvidx_off = faces_off + 3LL*((long long)Nm1 + 2LL*Nm2) + UVS_FLOATS;
  u64 ps = psum[t];
  int m1v = (int)(ps >> 44), m2v = (int)((ps >> 24) & 0xFFFFF);
  int seq = (int)(ps & 0xFFFFFF);
  int4 v4 = ((const int4*)tet)[t];
  int vv[4] = {v4.x, v4.y, v4.z, v4.w};
  int er[6];
  int j = 0;
  #pragma unroll
  for (int e = 0; e < 6; e++){
    int i0 = c_edges[2*e], i1 = c_edges[2*e+1];
    if (((pat >> i0) & 1) != ((pat >> i1) & 1)){
      int a = vv[i0], b = vv[i1]; if (a > b){ int tm = a; a = b; b = tm; }
      er[e] = binPref[a >> BSH] + (int)meta16[seq + j];
      j++;
    } else er[e] = -1;
  }
  for (int k = 0; k < nt_; k++){
    long long row = (nt_ == 1) ? (long long)m1v : ((long long)Nm1 + 2LL*m2v + k);
    #pragma unroll
    for (int c = 0; c < 3; c++){
      int slot = c_tri[pat][3*k + c];
      out[faces_off + 3*row + c] = (float)er[slot];
    }
    out[uvidx_off + 3*row + 0] = (float)(4*t);
    out[uvidx_off + 3*row + 1] = (float)(4*t + k + 1);
    out[uvidx_off + 3*row + 2] = (float)(4*t + k + 2);
  }
}

__global__ void k_uvs(const u64* __restrict__ psum, const int* __restrict__ binPref,
                      float* __restrict__ out){
  long long r = (long long)blockIdx.x*256 + threadIdx.x;
  if (r >= UVS_ROWS) return;
  u64 tot = psum[kNT];
  int Nm1 = (int)(tot >> 44), Nm2 = (int)((tot >> 24) & 0xFFFFF);
  int Ne = binPref[NBIN];
  long long off = 3LL*Ne + 3LL*((long long)Nm1 + 2LL*Nm2);
  int cell = (int)(r >> 2), k = (int)(r & 3);
  int iy = cell / kNUV, ix = cell - iy*kNUV;
  const float delta = (1.0f - 1.0f/895.0f) / 894.0f;   // linspace(0, 1-1/N, N) step, f32
  const float pad = 0.9f / 895.0f;
  float x = (float)ix * delta, y = (float)iy * delta;
  float u = x + ((k == 1 || k == 2) ? pad : 0.0f);
  float v = y + ((k >= 2) ? pad : 0.0f);
  if ((off & 1) == 0){                       // 8B-aligned fast path (uniform branch)
    float2 uv = make_float2(u, v);
    *reinterpret_cast<float2*>(&out[off + 2*r]) = uv;
  } else {
    out[off + 2*r]     = u;
    out[off + 2*r + 1] = v;
  }
}

// ---------------- host ----------------
static inline int divup(int a, int b){ return (a + b - 1) / b; }

extern "C" void kernel_launch(void* const* d_in, const int* in_sizes, int n_in,
                              void* d_out, int out_size, void* d_ws, size_t ws_size,
                              hipStream_t stream){
  const float* pos = (const float*)d_in[0];
  const float* sdf = (const float*)d_in[1];
  const int*   tet = (const int*)d_in[2];
  float* out = (float*)d_out;

  char* ws = (char*)d_ws;
  size_t off = 0;
  auto alloc = [&](size_t bytes) -> char* {
    char* p = ws + off; off += (bytes + 255) & ~(size_t)255; return p;
  };
  int* tetinfo      = (int*)alloc((size_t)kNT*4);
  u64* psum         = (u64*)alloc((size_t)(kNT+1)*8);
  int* blockHist    = (int*)alloc((size_t)NBIN*NH*4);
  int* bhScan       = (int*)alloc((size_t)(NBIN*NH+1)*4);
  u64* ebin         = (u64*)alloc((size_t)CAP*8);
  u64* vfirst       = (u64*)alloc((size_t)CAP*8);
  u16* meta16       = (u16*)alloc((size_t)CAP*2);
  int* binFirstCnt  = (int*)alloc((size_t)(NBIN+1)*4);
  u64* pkPart       = (u64*)alloc((size_t)NH*8);
  int* partI        = (int*)alloc(4096*4);
  if (off > ws_size){
    fprintf(stderr, "[dmtet] workspace too small: need %zu have %zu\n", off, ws_size);
    return;
  }

  k_classify_hist<<<NH, 256, 0, stream>>>(tet, sdf, tetinfo, blockHist, pkPart);
  // psum: classify's per-block sums are the scan partials (TILE_T == SCAN_TILE)
  k_scan_blocksums<u64><<<1, SCAN_B, 0, stream>>>(pkPart, NH, psum + kNT);
  k_scan_apply_pk<<<divup(kNT,SCAN_TILE), SCAN_B, 0, stream>>>(tetinfo, psum, pkPart);
  run_scan<int>(blockHist, bhScan, NBIN*NH, partI, stream);
  k_scatter<<<NH2, SBLK, 0, stream>>>(tet, tetinfo, psum, bhScan, ebin);
  k_fineflags<<<NBIN, 256, 0, stream>>>(bhScan, ebin, meta16, vfirst, binFirstCnt);
  k_scan_blocksums<int><<<1, SCAN_B, 0, stream>>>(binFirstCnt, NBIN, binFirstCnt + NBIN);
  k_verts<<<NBIN, 256, 0, stream>>>(bhScan, vfirst, binFirstCnt, pos, sdf, out);
  k_faces<<<divup(kNT,256), 256, 0, stream>>>(tet, tetinfo, psum, binFirstCnt, meta16, out);
  k_uvs<<<divup((int)UVS_ROWS,256), 256, 0, stream>>>(psum, binFirstCnt, out);
}

// Round 22
// 202.031 us; speedup vs baseline: 1.0233x; 1.0233x over previous
//
#include <hip/hip_runtime.h>
#include <cstdio>
#include <cstdint>

typedef unsigned long long u64;
typedef unsigned short u16;
typedef unsigned int u32;

// ---------------- problem constants ----------------
static const int kNV = 200000;
static const int kNT = 800000;
static const int kNUV = 895;                       // ceil(sqrt((2*NT+1)//2))
#define UVS_ROWS   3204100LL                       // kNUV*kNUV*4
#define UVS_FLOATS 6408200LL                       // UVS_ROWS*2
#define CAP 3300000                                // max crossing-edge instances (<= 4*NT = 3.2M)

// counting-sort geometry (R15/R19-proven)
#define NH 392                                     // classify/scatter blocks
#define TILE_T 2048                                // tets per block
#define BINW 64                                    // a-values per coarse bin
#define BSH 6                                      // log2(BINW)
#define NBIN 3125                                  // 200000/64
#define SUBSH 15                                   // group key = (a, b>>SUBSH) == fine key
#define FINEB 512                                  // BINW * (1<<(18-SUBSH)) fine cursors
#define MAXBIN 2816                                // LDS bin capacity
#define C 11                                       // MAXBIN/256 items per thread
#define FLW (MAXBIN/32)                            // 88 first-flag bitmask words

__device__ const int c_tri[16][6] = {
    {-1,-1,-1,-1,-1,-1},{1,0,2,-1,-1,-1},{4,0,3,-1,-1,-1},{1,4,2,1,3,4},
    {3,1,5,-1,-1,-1},{2,3,0,2,5,3},{1,4,0,1,5,4},{4,2,5,-1,-1,-1},
    {4,5,2,-1,-1,-1},{4,1,0,4,5,1},{3,2,0,3,5,2},{1,3,5,-1,-1,-1},
    {4,1,2,4,3,1},{3,0,4,-1,-1,-1},{2,0,1,-1,-1,-1},{-1,-1,-1,-1,-1,-1}};
__device__ const int c_ntri[16]   = {0,1,1,2,1,2,2,1,1,2,2,1,2,1,1,0};
__device__ const int c_ncross[16] = {0,3,3,4,3,4,4,3,3,4,4,3,4,3,3,0};
__device__ const int c_edges[12] = {0,1,0,2,0,3,1,2,1,3,2,3};

// psum packing: m1 <<44 | m2 <<24 | ncross
#define PK(m1,m2,nc) (((u64)(m1) << 44) | ((u64)(m2) << 24) | (u64)(nc))
// ebin packing: a <<40 | b <<22 | seq
// lk: (a-a0)<<18 | b  (24-bit bin-local key; fine key = lk>>SUBSH)
// meta16BySeq: rp only; bin recomputed in k_faces from tet

// block-wide exclusive scan of one int per thread (256 thr) via shfl; 2 barriers.
__device__ __forceinline__ int blockScanExcl(int v, volatile int* wsum, int tid, int* totalOut){
  int lane = tid & 63, wv = tid >> 6;
  int x = v;
  #pragma unroll
  for (int off = 1; off < 64; off <<= 1){
    int t = __shfl_up(x, off, 64);
    if (lane >= off) x += t;
  }
  __syncthreads();                 // protect wsum from prior use
  if (lane == 63) wsum[wv] = x;
  __syncthreads();
  int carry = 0;
  #pragma unroll
  for (int w = 0; w < 4; w++) if (w < wv) carry += wsum[w];
  if (totalOut) *totalOut = wsum[0] + wsum[1] + wsum[2] + wsum[3];
  return carry + x - v;
}

// ---------------- generic exclusive scan (templated, 3 kernels) ----------------
#define SCAN_B 256
#define SCAN_I 8
#define SCAN_TILE (SCAN_B*SCAN_I)

template<typename T>
__global__ void k_scan_partial(const T* __restrict__ in, T* __restrict__ partials, int n){
  __shared__ T sm[SCAN_B];
  int b = blockIdx.x;
  long long base = (long long)b*SCAN_TILE;
  T sum = 0;
  for (int i = threadIdx.x; i < SCAN_TILE; i += SCAN_B){
    long long idx = base + i;
    if (idx < n) sum += in[idx];
  }
  sm[threadIdx.x] = sum; __syncthreads();
  for (int s = SCAN_B/2; s > 0; s >>= 1){
    if ((int)threadIdx.x < s) sm[threadIdx.x] += sm[threadIdx.x + s];
    __syncthreads();
  }
  if (threadIdx.x == 0) partials[b] = sm[0];
}

template<typename T>
__global__ void k_scan_blocksums(T* __restrict__ partials, int nb, T* __restrict__ total_out){
  __shared__ T sm[SCAN_B];
  T carry = 0;
  for (int base = 0; base < nb; base += SCAN_B){
    int i = base + (int)threadIdx.x;
    T v = (i < nb) ? partials[i] : (T)0;
    sm[threadIdx.x] = v; __syncthreads();
    for (int off = 1; off < SCAN_B; off <<= 1){
      T t = ((int)threadIdx.x >= off) ? sm[threadIdx.x - off] : (T)0;
      __syncthreads();
      sm[threadIdx.x] += t;
      __syncthreads();
    }
    if (i < nb) partials[i] = carry + sm[threadIdx.x] - v;  // exclusive
    T tilesum = sm[SCAN_B-1];
    __syncthreads();
    carry += tilesum;
  }
  if (threadIdx.x == 0 && total_out) *total_out = carry;
}

template<typename T>
__global__ void k_scan_apply(const T* __restrict__ in, T* __restrict__ out,
                             const T* __restrict__ partials, int n){
  __shared__ T sm[SCAN_B];
  int b = blockIdx.x;
  long long base = (long long)b*SCAN_TILE + (long long)threadIdx.x*SCAN_I;
  T v[SCAN_I]; T s = 0;
  #pragma unroll
  for (int k = 0; k < SCAN_I; k++){ long long idx = base + k; v[k] = (idx < n) ? in[idx] : (T)0; s += v[k]; }
  sm[threadIdx.x] = s; __syncthreads();
  for (int off = 1; off < 256; off <<= 1){
    T t = ((int)threadIdx.x >= off) ? sm[threadIdx.x - off] : (T)0;
    __syncthreads();
    sm[threadIdx.x] += t;
    __syncthreads();
  }
  T excl = sm[threadIdx.x] - s + partials[b];
  #pragma unroll
  for (int k = 0; k < SCAN_I; k++){ long long idx = base + k; if (idx < n) out[idx] = excl; excl += v[k]; }
}

template<typename T>
static void run_scan(const T* in, T* out, int n, T* partials, hipStream_t s){
  int nb = (n + SCAN_TILE - 1) / SCAN_TILE;
  k_scan_partial<T><<<nb, SCAN_B, 0, s>>>(in, partials, n);
  k_scan_blocksums<T><<<1, SCAN_B, 0, s>>>(partials, nb, out + n);  // total -> out[n]
  k_scan_apply<T><<<nb, SCAN_B, 0, s>>>(in, out, partials, n);
}

// psum apply: recompute PK values from tetinfo (no pk array); partials = pre-scanned pkPart
__global__ void k_scan_apply_pk(const int* __restrict__ tetinfo, u64* __restrict__ out,
                                const u64* __restrict__ partials){
  __shared__ u64 sm[SCAN_B];
  int b = blockIdx.x;
  long long base = (long long)b*SCAN_TILE + (long long)threadIdx.x*SCAN_I;
  u64 v[SCAN_I]; u64 s = 0;
  #pragma unroll
  for (int k = 0; k < SCAN_I; k++){
    long long idx = base + k;
    if (idx < kNT){
      int pat = tetinfo[idx];
      int nt_ = c_ntri[pat];
      v[k] = PK(nt_ == 1, nt_ == 2, c_ncross[pat]);
    } else v[k] = 0;
    s += v[k];
  }
  sm[threadIdx.x] = s; __syncthreads();
  for (int off = 1; off < 256; off <<= 1){
    u64 t = ((int)threadIdx.x >= off) ? sm[threadIdx.x - off] : (u64)0;
    __syncthreads();
    sm[threadIdx.x] += t;
    __syncthreads();
  }
  u64 excl = sm[threadIdx.x] - s + partials[b];
  #pragma unroll
  for (int k = 0; k < SCAN_I; k++){ long long idx = base + k; if (idx < kNT) out[idx] = excl; excl += v[k]; }
}

// ---------------- pipeline kernels ----------------

// fused: per-tet pattern + coarse-bin histogram (bin-major for the generic scan) + PK sums
__global__ void k_classify_hist(const int* __restrict__ tet, const float* __restrict__ sdf,
                                int* __restrict__ tetinfo, int* __restrict__ blockHist,
                                u64* __restrict__ pkPart){
  __shared__ int h[NBIN];
  __shared__ u64 red[256];
  int blk = blockIdx.x;
  for (int j = threadIdx.x; j < NBIN; j += 256) h[j] = 0;
  __syncthreads();
  int t0 = blk*TILE_T;
  u64 myPk = 0;
  for (int k = 0; k < TILE_T/256; k++){
    int t = t0 + k*256 + threadIdx.x;
    if (t < kNT){
      int4 v4 = ((const int4*)tet)[t];
      int pat = ((sdf[v4.x] > 0.0f) ? 1 : 0) | ((sdf[v4.y] > 0.0f) ? 2 : 0)
              | ((sdf[v4.z] > 0.0f) ? 4 : 0) | ((sdf[v4.w] > 0.0f) ? 8 : 0);
      tetinfo[t] = pat;
      int nt_ = c_ntri[pat];
      myPk += PK(nt_ == 1, nt_ == 2, c_ncross[pat]);
      if (pat != 0 && pat != 15){
        int vv[4] = {v4.x, v4.y, v4.z, v4.w};
        #pragma unroll
        for (int e = 0; e < 6; e++){
          int i0 = c_edges[2*e], i1 = c_edges[2*e+1];
          if (((pat >> i0) & 1) != ((pat >> i1) & 1)){
            int a = vv[i0], b = vv[i1]; if (a > b){ int tm = a; a = b; b = tm; }
            atomicAdd(&h[a >> BSH], 1);
          }
        }
      }
    }
  }
  red[threadIdx.x] = myPk;
  __syncthreads();
  for (int s = 128; s > 0; s >>= 1){
    if ((int)threadIdx.x < s) red[threadIdx.x] += red[threadIdx.x + s];
    __syncthreads();
  }
  if (threadIdx.x == 0) pkPart[blk] = red[0];
  for (int j = threadIdx.x; j < NBIN; j += 256) blockHist[j*NH + blk] = h[j];  // bin-major
}

// scatter instances to bin-grouped buffer via LDS cursors (payload = seq)
__global__ void k_scatter(const int* __restrict__ tet, const int* __restrict__ tetinfo,
                          const u64* __restrict__ psum, const int* __restrict__ bhScan,
                          u64* __restrict__ ebin){
  __shared__ int c[NBIN];
  int blk = blockIdx.x;
  for (int j = threadIdx.x; j < NBIN; j += 256) c[j] = bhScan[j*NH + blk];
  __syncthreads();
  int t0 = blk*TILE_T;
  for (int k = 0; k < TILE_T/256; k++){
    int t = t0 + k*256 + threadIdx.x;
    if (t < kNT){
      int pat = tetinfo[t];
      if (pat != 0 && pat != 15){
        int4 v4 = ((const int4*)tet)[t];
        int vv[4] = {v4.x, v4.y, v4.z, v4.w};
        int seq = (int)(psum[t] & 0xFFFFFF);
        #pragma unroll
        for (int e = 0; e < 6; e++){
          int i0 = c_edges[2*e], i1 = c_edges[2*e+1];
          if (((pat >> i0) & 1) != ((pat >> i1) & 1)){
            int a = vv[i0], b = vv[i1]; if (a > b){ int tm = a; a = b; b = tm; }
            int pos = atomicAdd(&c[a >> BSH], 1);
            ebin[pos] = ((u64)(unsigned)a << 40) | ((u64)(unsigned)b << 22) | (unsigned)seq;
            seq++;
          }
        }
      }
    }
  }
}

// per coarse bin: each thread processes the items IT scattered (lk/sq/pos in registers);
// LDS = lk(u32) + flag bitmask + word-prefix + h  (~14KB -> 8 blocks/CU, 2x occupancy).
__global__ __launch_bounds__(256, 6)
void k_fineflags(const int* __restrict__ bhScan, const u64* __restrict__ ebin,
                 u16* __restrict__ meta16, u64* __restrict__ vfirst,
                 int* __restrict__ binFirstCnt){
  __shared__ u32 lk[MAXBIN];             // 11.3 KB  24-bit bin-local keys
  __shared__ u32 flb[FLW];               // 352 B    first-flag bitmask
  __shared__ int fpw[FLW];               // 352 B    word-level exclusive popcount prefix
  __shared__ int h[FINEB];               // 2 KB     fine-key cursors / run ends
  __shared__ int wsum[4];
  int bin = blockIdx.x, tid = threadIdx.x;
  int bs = bhScan[bin*NH];
  int be = bhScan[(bin+1)*NH];           // scan stores total at [n] for the last bin
  int n = be - bs;
  int a0 = bin << BSH;
  for (int j = tid; j < FINEB; j += 256) h[j] = 0;
  if (tid < FLW) flb[tid] = 0;
  __syncthreads();
  if (n <= MAXBIN){
    // stage owned items into registers (single ebin pass)
    u32 lkr[C], sqr[C]; int kr[C], posr[C]; unsigned char fR[C];
    #pragma unroll
    for (int k = 0; k < C; k++){
      int i = tid + k*256;
      if (i < n){
        u64 p = ebin[bs + i];
        int a = (int)(p >> 40);
        u32 b = (u32)((p >> 22) & 0x3FFFF);
        lkr[k] = ((u32)(a - a0) << 18) | b;
        sqr[k] = (u32)(p & 0x3FFFFF);
        kr[k] = (int)(lkr[k] >> SUBSH);
      } else kr[k] = -1;
    }
    // hist
    #pragma unroll
    for (int k = 0; k < C; k++) if (kr[k] >= 0) atomicAdd(&h[kr[k]], 1);
    __syncthreads();
    // exclusive scan of h[512] (2/thread, shfl-based)
    int s0 = h[2*tid], s1 = h[2*tid+1];
    int excl = blockScanExcl(s0 + s1, wsum, tid, nullptr);
    h[2*tid] = excl; h[2*tid+1] = excl + s0;
    __syncthreads();
    // scatter keys into LDS; remember own positions
    #pragma unroll
    for (int k = 0; k < C; k++){
      if (kr[k] >= 0){
        int pos = atomicAdd(&h[kr[k]], 1);
        lk[pos] = lkr[k];
        posr[k] = pos;
      }
    }
    __syncthreads();
    // phase A: first flag per owned item (backward dup-scan over [gs, pos))
    #pragma unroll
    for (int k = 0; k < C; k++){
      fR[k] = 0;
      if (kr[k] >= 0){
        int gs = kr[k] ? h[kr[k]-1] : 0;
        unsigned char f = 1;
        for (int y = posr[k]-1; y >= gs; y--){ if (lk[y] == lkr[k]){ f = 0; break; } }
        fR[k] = f;
        if (f) atomicOr(&flb[posr[k] >> 5], 1u << (posr[k] & 31));
      }
    }
    __syncthreads();
    // phase B: word-level exclusive prefix of flag popcounts
    int v = (tid < FLW) ? (int)__popc(flb[tid]) : 0;
    int tot;
    int ex2 = blockScanExcl(v, wsum, tid, &tot);
    if (tid < FLW) fpw[tid] = ex2;
    if (tid == 0) binFirstCnt[bin] = tot;
    __syncthreads();
    // phase C: rank over [gs, ge); rp = fp[gs] + rank; outputs from registers
    #pragma unroll
    for (int k = 0; k < C; k++){
      if (kr[k] >= 0){
        int gs = kr[k] ? h[kr[k]-1] : 0;
        int ge = h[kr[k]];
        u32 my = lkr[k];
        int rk = 0;
        for (int y = gs; y < ge; y++){
          if (lk[y] < my && ((flb[y >> 5] >> (y & 31)) & 1u)) rk++;
        }
        int fpgs = fpw[gs >> 5] + (int)__popc(flb[gs >> 5] & ((1u << (gs & 31)) - 1u));
        int rp = fpgs + rk;               // bin-local sorted rank of this distinct edge
        meta16[(int)sqr[k]] = (u16)rp;
        if (fR[k]){
          u64 p = ((u64)(unsigned)(a0 + (int)(my >> 18)) << 40)
                | ((u64)(my & 0x3FFFF) << 22) | sqr[k];
          vfirst[bs + rp] = p;            // rp bijective over firsts -> sorted stream
        }
      }
    }
  } else {
    // fallback (statistically never): serial O(n^2) by thread 0 straight from ebin
    if (tid == 0){
      int fcnt = 0;
      for (int x = 0; x < n; x++){
        u64 px = ebin[bs+x];
        u64 kx = px >> 22;
        int f = 1;
        for (int y = 0; y < x; y++) if ((ebin[bs+y] >> 22) == kx){ f = 0; break; }
        int rp = 0;
        for (int y = 0; y < n; y++){
          u64 ky = ebin[bs+y] >> 22;
          if (ky < kx){
            int fy = 1;
            for (int z = 0; z < y; z++) if ((ebin[bs+z] >> 22) == ky){ fy = 0; break; }
            rp += fy;
          }
        }
        if (f){ vfirst[bs + rp] = px; fcnt++; }
        meta16[(int)(px & 0x3FFFFF)] = (u16)rp;
      }
      binFirstCnt[bin] = fcnt;
    }
  }
}

// per-bin verts: sequential reads of compacted firsts; sequential vert writes
__global__ void k_verts(const int* __restrict__ bhScan, const u64* __restrict__ vfirst,
                        const int* __restrict__ binPref, const float* __restrict__ pos,
                        const float* __restrict__ sdf, float* __restrict__ out){
  int bin = blockIdx.x;
  int bs = bhScan[bin*NH];
  int rbase = binPref[bin];
  int cnt = binPref[bin+1] - rbase;
  for (int f = threadIdx.x; f < cnt; f += 256){
    u64 p = vfirst[bs + f];
    int a = (int)(p >> 40);
    int b = (int)((p >> 22) & 0x3FFFF);
    float sa = sdf[a], sb = sdf[b];
    float denom = sa - sb;               // s = [sa,-sb]; never 0 for a crossing edge
    float w0 = (-sb) / denom;
    float w1 = sa / denom;
    long long r = rbase + f;
    out[3*r + 0] = pos[3*a+0]*w0 + pos[3*b+0]*w1;
    out[3*r + 1] = pos[3*a+1]*w0 + pos[3*b+1]*w1;
    out[3*r + 2] = pos[3*a+2]*w0 + pos[3*b+2]*w1;
  }
}

// faces + uv_idx: recompute bin from tet (a>>BSH); r = binPref[bin] + meta16[seq+j]
__global__ void k_faces(const int* __restrict__ tet, const int* __restrict__ tetinfo,
                        const u64* __restrict__ psum, const int* __restrict__ binPref,
                        const u16* __restrict__ meta16, float* __restrict__ out){
  int t = blockIdx.x*256 + threadIdx.x; if (t >= kNT) return;
  int pat = tetinfo[t];
  int nt_ = c_ntri[pat];
  if (nt_ == 0) return;
  u64 tot = psum[kNT];
  int Nm1 = (int)(tot >> 44), Nm2 = (int)((tot >> 24) & 0xFFFFF);
  int Ne = binPref[NBIN];
  long long faces_off = 3LL*Ne;
  long long uvidx_off = faces_off + 3LL*((long long)Nm1 + 2LL*Nm2) + UVS_FLOATS;
  u64 ps = psum[t];
  int m1v = (int)(ps >> 44), m2v = (int)((ps >> 24) & 0xFFFFF);
  int seq = (int)(ps & 0xFFFFFF);
  int4 v4 = ((const int4*)tet)[t];
  int vv[4] = {v4.x, v4.y, v4.z, v4.w};
  int er[6];
  int j = 0;
  #pragma unroll
  for (int e = 0; e < 6; e++){
    int i0 = c_edges[2*e], i1 = c_edges[2*e+1];
    if (((pat >> i0) & 1) != ((pat >> i1) & 1)){
      int a = vv[i0], b = vv[i1]; if (a > b){ int tm = a; a = b; b = tm; }
      er[e] = binPref[a >> BSH] + (int)meta16[seq + j];
      j++;
    } else er[e] = -1;
  }
  for (int k = 0; k < nt_; k++){
    long long row = (nt_ == 1) ? (long long)m1v : ((long long)Nm1 + 2LL*m2v + k);
    #pragma unroll
    for (int c = 0; c < 3; c++){
      int slot = c_tri[pat][3*k + c];
      out[faces_off + 3*row + c] = (float)er[slot];
    }
    out[uvidx_off + 3*row + 0] = (float)(4*t);
    out[uvidx_off + 3*row + 1] = (float)(4*t + k + 1);
    out[uvidx_off + 3*row + 2] = (float)(4*t + k + 2);
  }
}

__global__ void k_uvs(const u64* __restrict__ psum, const int* __restrict__ binPref,
                      float* __restrict__ out){
  long long r = (long long)blockIdx.x*256 + threadIdx.x;
  if (r >= UVS_ROWS) return;
  u64 tot = psum[kNT];
  int Nm1 = (int)(tot >> 44), Nm2 = (int)((tot >> 24) & 0xFFFFF);
  int Ne = binPref[NBIN];
  long long off = 3LL*Ne + 3LL*((long long)Nm1 + 2LL*Nm2);
  int cell = (int)(r >> 2), k = (int)(r & 3);
  int iy = cell / kNUV, ix = cell - iy*kNUV;
  const float delta = (1.0f - 1.0f/895.0f) / 894.0f;   // linspace(0, 1-1/N, N) step, f32
  const float pad = 0.9f / 895.0f;
  float x = (float)ix * delta, y = (float)iy * delta;
  float u = x + ((k == 1 || k == 2) ? pad : 0.0f);
  float v = y + ((k >= 2) ? pad : 0.0f);
  if ((off & 1) == 0){                       // 8B-aligned fast path (uniform branch)
    float2 uv = make_float2(u, v);
    *reinterpret_cast<float2*>(&out[off + 2*r]) = uv;
  } else {
    out[off + 2*r]     = u;
    out[off + 2*r + 1] = v;
  }
}

// ---------------- host ----------------
static inline int divup(int a, int b){ return (a + b - 1) / b; }

extern "C" void kernel_launch(void* const* d_in, const int* in_sizes, int n_in,
                              void* d_out, int out_size, void* d_ws, size_t ws_size,
                              hipStream_t stream){
  const float* pos = (const float*)d_in[0];
  const float* sdf = (const float*)d_in[1];
  const int*   tet = (const int*)d_in[2];
  float* out = (float*)d_out;

  char* ws = (char*)d_ws;
  size_t off = 0;
  auto alloc = [&](size_t bytes) -> char* {
    char* p = ws + off; off += (bytes + 255) & ~(size_t)255; return p;
  };
  int* tetinfo      = (int*)alloc((size_t)kNT*4);
  u64* psum         = (u64*)alloc((size_t)(kNT+1)*8);
  int* blockHist    = (int*)alloc((size_t)NBIN*NH*4);
  int* bhScan       = (int*)alloc((size_t)(NBIN*NH+1)*4);
  u64* ebin         = (u64*)alloc((size_t)CAP*8);
  u64* vfirst       = (u64*)alloc((size_t)CAP*8);
  u16* meta16       = (u16*)alloc((size_t)CAP*2);
  int* binFirstCnt  = (int*)alloc((size_t)(NBIN+1)*4);
  u64* pkPart       = (u64*)alloc((size_t)NH*8);
  int* partI        = (int*)alloc(4096*4);
  if (off > ws_size){
    fprintf(stderr, "[dmtet] workspace too small: need %zu have %zu\n", off, ws_size);
    return;
  }

  k_classify_hist<<<NH, 256, 0, stream>>>(tet, sdf, tetinfo, blockHist, pkPart);
  // psum: classify's per-block sums are the scan partials (TILE_T == SCAN_TILE)
  k_scan_blocksums<u64><<<1, SCAN_B, 0, stream>>>(pkPart, NH, psum + kNT);
  k_scan_apply_pk<<<divup(kNT,SCAN_TILE), SCAN_B, 0, stream>>>(tetinfo, psum, pkPart);
  run_scan<int>(blockHist, bhScan, NBIN*NH, partI, stream);
  k_scatter<<<NH, 256, 0, stream>>>(tet, tetinfo, psum, bhScan, ebin);
  k_fineflags<<<NBIN, 256, 0, stream>>>(bhScan, ebin, meta16, vfirst, binFirstCnt);
  k_scan_blocksums<int><<<1, SCAN_B, 0, stream>>>(binFirstCnt, NBIN, binFirstCnt + NBIN);
  k_verts<<<NBIN, 256, 0, stream>>>(bhScan, vfirst, binFirstCnt, pos, sdf, out);
  k_faces<<<divup(kNT,256), 256, 0, stream>>>(tet, tetinfo, psum, binFirstCnt, meta16, out);
  k_uvs<<<divup((int)UVS_ROWS,256), 256, 0, stream>>>(psum, binFirstCnt, out);
}